// Round 2
// baseline (81.313 us; speedup 1.0000x reference)
//
#include <hip/hip_runtime.h>

// HardNMS fused kernel, register-sliding-window version.
// x: [B=16, 2, H=1024, W=1024] f32 -> out: [16, 1, 1024, 1024] f32
// xp   = relu(x[:,1] - x[:,0] - 0.1)
// xNMS = 256 * prod_{8 nbrs} relu(xp - xp_nb)   (zero-padded)
// out  = xp * maxpool3x3(xNMS)                  (xNMS >= 0 so zero-pad == -inf pad)

constexpr int Wd = 1024, Hd = 1024, Bd = 16;
constexpr int TX = 128, TY = 32;          // output tile per block
constexpr int RXP = 136;                  // staged cols: x0-4 .. x0+131 (f4-aligned)
constexpr int RY  = 36;                   // staged rows: y0-2 .. y0+33
constexpr float EPS = 0.1f;

__device__ __forceinline__ float max3(float a, float b, float c) {
    return fmaxf(fmaxf(a, b), c);
}

__global__ __launch_bounds__(256, 6) void hardnms_kernel(
    const float* __restrict__ xin, float* __restrict__ out) {
    __shared__ float sxp[RY][RXP];

    const int x0 = blockIdx.x * TX;
    const int y0 = blockIdx.y * TY;
    const int b  = blockIdx.z;
    const float* __restrict__ p0 = xin + (size_t)(b * 2 + 0) * Hd * Wd;
    const float* __restrict__ p1 = xin + (size_t)(b * 2 + 1) * Hd * Wd;
    const int tid = threadIdx.x;

    // ---- Phase 1: stage xp into LDS with float4 loads ----
    constexpr int F4W = RXP / 4;          // 34 float4 per row
    constexpr int NF4 = RY * F4W;         // 1224
    for (int i = tid; i < NF4; i += 256) {
        const int ry  = i / F4W;
        const int rxf = i - ry * F4W;
        const int gy  = y0 + ry - 2;
        const int gx  = x0 + rxf * 4 - 4;
        float4 v = make_float4(0.f, 0.f, 0.f, 0.f);
        if ((unsigned)gy < (unsigned)Hd) {
            const size_t ro = (size_t)gy * Wd;
            if (gx >= 0 && gx + 3 < Wd) {
                const float4 a = *(const float4*)(p0 + ro + gx);
                const float4 c = *(const float4*)(p1 + ro + gx);
                v.x = fmaxf(c.x - a.x - EPS, 0.f);
                v.y = fmaxf(c.y - a.y - EPS, 0.f);
                v.z = fmaxf(c.z - a.z - EPS, 0.f);
                v.w = fmaxf(c.w - a.w - EPS, 0.f);
            } else {
                float t[4];
                #pragma unroll
                for (int e = 0; e < 4; ++e) {
                    const int gxe = gx + e;
                    t[e] = ((unsigned)gxe < (unsigned)Wd)
                         ? fmaxf(p1[ro + gxe] - p0[ro + gxe] - EPS, 0.f) : 0.f;
                }
                v = make_float4(t[0], t[1], t[2], t[3]);
            }
        }
        *(float4*)(&sxp[ry][rxf * 4]) = v;
    }
    __syncthreads();

    // ---- Phase 2: per-thread 4x4 output patch, sliding window in y ----
    const int tx   = tid & 31;
    const int tyt  = tid >> 5;
    const int xloc = tx * 4;      // first output tile-col
    const int r0   = tyt * 4;     // first output tile-row; LDS row = tile row + 2

    // load span: s[i] = xp at tile col (xloc-2+i), i=0..7; LDS col = tile col + 4
    #define LOAD_ROW(lr, s) do {                                            \
        const float* rp_ = &sxp[(lr)][0];                                   \
        const float4 a_ = *(const float4*)(rp_ + xloc);                     \
        const float4 b_ = *(const float4*)(rp_ + xloc + 4);                 \
        const float4 d_ = *(const float4*)(rp_ + xloc + 8);                 \
        s[0]=a_.z; s[1]=a_.w; s[2]=b_.x; s[3]=b_.y;                         \
        s[4]=b_.z; s[5]=b_.w; s[6]=d_.x; s[7]=d_.y;                         \
    } while (0)

    // xNMS row (6 wide, tile cols xloc-1..xloc+4) + 3-wide rowmax -> rm[4]
    #define ROWMAX_NM(A, B, C, rm) do {                                     \
        float nm_[6];                                                       \
        _Pragma("unroll")                                                   \
        for (int j = 0; j < 6; ++j) {                                       \
            const float c_ = B[j + 1];                                      \
            float p_;                                                       \
            p_  = fmaxf(c_ - A[j    ], 0.f);                                \
            p_ *= fmaxf(c_ - A[j + 1], 0.f);                                \
            p_ *= fmaxf(c_ - A[j + 2], 0.f);                                \
            p_ *= fmaxf(c_ - B[j    ], 0.f);                                \
            p_ *= fmaxf(c_ - B[j + 2], 0.f);                                \
            p_ *= fmaxf(c_ - C[j    ], 0.f);                                \
            p_ *= fmaxf(c_ - C[j + 1], 0.f);                                \
            p_ *= fmaxf(c_ - C[j + 2], 0.f);                                \
            nm_[j] = p_;                                                    \
        }                                                                   \
        rm[0] = max3(nm_[0], nm_[1], nm_[2]);                               \
        rm[1] = max3(nm_[1], nm_[2], nm_[3]);                               \
        rm[2] = max3(nm_[2], nm_[3], nm_[4]);                               \
        rm[3] = max3(nm_[3], nm_[4], nm_[5]);                               \
    } while (0)

    float R0[8], R1[8], R2[8], R3[8];
    float rmP[4], rmC[4], rmN[4];

    LOAD_ROW(r0 + 0, R0);                 // tile row r0-2
    LOAD_ROW(r0 + 1, R1);                 // tile row r0-1
    LOAD_ROW(r0 + 2, R2);                 // tile row r0
    ROWMAX_NM(R0, R1, R2, rmP);           // nm row r0-1
    LOAD_ROW(r0 + 3, R3);                 // tile row r0+1
    ROWMAX_NM(R1, R2, R3, rmC);           // nm row r0

    float* __restrict__ po = out + (size_t)b * Hd * Wd
                           + (size_t)(y0 + r0) * Wd + (x0 + xloc);

    #define EMIT(CTR, ra, rb, rc) do {                                      \
        float4 o_;                                                          \
        o_.x = CTR[2] * 256.f * max3(ra[0], rb[0], rc[0]);                  \
        o_.y = CTR[3] * 256.f * max3(ra[1], rb[1], rc[1]);                  \
        o_.z = CTR[4] * 256.f * max3(ra[2], rb[2], rc[2]);                  \
        o_.w = CTR[5] * 256.f * max3(ra[3], rb[3], rc[3]);                  \
        *(float4*)po = o_;                                                  \
        po += Wd;                                                           \
    } while (0)

    // k=0: output row r0; nm row r0+1 needs tile rows r0..r0+2 (R2,R3,new R0)
    LOAD_ROW(r0 + 4, R0);
    ROWMAX_NM(R2, R3, R0, rmN);
    EMIT(R2, rmP, rmC, rmN);

    // k=1: output row r0+1; nm row r0+2 needs R3,R0,new R1
    LOAD_ROW(r0 + 5, R1);
    ROWMAX_NM(R3, R0, R1, rmP);
    EMIT(R3, rmC, rmN, rmP);

    // k=2: output row r0+2; nm row r0+3 needs R0,R1,new R2
    LOAD_ROW(r0 + 6, R2);
    ROWMAX_NM(R0, R1, R2, rmC);
    EMIT(R0, rmN, rmP, rmC);

    // k=3: output row r0+3; nm row r0+4 needs R1,R2,new R3
    LOAD_ROW(r0 + 7, R3);
    ROWMAX_NM(R1, R2, R3, rmN);
    EMIT(R1, rmP, rmC, rmN);

    #undef LOAD_ROW
    #undef ROWMAX_NM
    #undef EMIT
}

extern "C" void kernel_launch(void* const* d_in, const int* in_sizes, int n_in,
                              void* d_out, int out_size, void* d_ws, size_t ws_size,
                              hipStream_t stream) {
    const float* xin = (const float*)d_in[0];
    float* out = (float*)d_out;
    dim3 grid(Wd / TX, Hd / TY, Bd);
    hardnms_kernel<<<grid, dim3(256), 0, stream>>>(xin, out);
}

// Round 3
// 56.253 us; speedup vs baseline: 1.4455x; 1.4455x over previous
//
#include <hip/hip_runtime.h>

// HardNMS fused kernel, register-sliding-window version (spill fix: LB 256,4).
// x: [B=16, 2, H=1024, W=1024] f32 -> out: [16, 1, 1024, 1024] f32
// xp   = relu(x[:,1] - x[:,0] - 0.1)
// xNMS = 256 * prod_{8 nbrs} relu(xp - xp_nb)   (zero-padded)
// out  = xp * maxpool3x3(xNMS)                  (xNMS >= 0 so zero-pad == -inf pad)

constexpr int Wd = 1024, Hd = 1024, Bd = 16;
constexpr int TX = 128, TY = 32;          // output tile per block
constexpr int RXP = 136;                  // staged cols: x0-4 .. x0+131 (f4-aligned)
constexpr int RY  = 36;                   // staged rows: y0-2 .. y0+33
constexpr float EPS = 0.1f;

__device__ __forceinline__ float max3(float a, float b, float c) {
    return fmaxf(fmaxf(a, b), c);
}

__global__ __launch_bounds__(256, 4) void hardnms_kernel(
    const float* __restrict__ xin, float* __restrict__ out) {
    __shared__ float sxp[RY][RXP];

    const int x0 = blockIdx.x * TX;
    const int y0 = blockIdx.y * TY;
    const int b  = blockIdx.z;
    const float* __restrict__ p0 = xin + (size_t)(b * 2 + 0) * Hd * Wd;
    const float* __restrict__ p1 = xin + (size_t)(b * 2 + 1) * Hd * Wd;
    const int tid = threadIdx.x;

    // ---- Phase 1: stage xp into LDS with float4 loads ----
    constexpr int F4W = RXP / 4;          // 34 float4 per row
    constexpr int NF4 = RY * F4W;         // 1224
    for (int i = tid; i < NF4; i += 256) {
        const int ry  = i / F4W;
        const int rxf = i - ry * F4W;
        const int gy  = y0 + ry - 2;
        const int gx  = x0 + rxf * 4 - 4;
        float4 v = make_float4(0.f, 0.f, 0.f, 0.f);
        if ((unsigned)gy < (unsigned)Hd) {
            const size_t ro = (size_t)gy * Wd;
            if (gx >= 0 && gx + 3 < Wd) {
                const float4 a = *(const float4*)(p0 + ro + gx);
                const float4 c = *(const float4*)(p1 + ro + gx);
                v.x = fmaxf(c.x - a.x - EPS, 0.f);
                v.y = fmaxf(c.y - a.y - EPS, 0.f);
                v.z = fmaxf(c.z - a.z - EPS, 0.f);
                v.w = fmaxf(c.w - a.w - EPS, 0.f);
            } else {
                float t[4];
                #pragma unroll
                for (int e = 0; e < 4; ++e) {
                    const int gxe = gx + e;
                    t[e] = ((unsigned)gxe < (unsigned)Wd)
                         ? fmaxf(p1[ro + gxe] - p0[ro + gxe] - EPS, 0.f) : 0.f;
                }
                v = make_float4(t[0], t[1], t[2], t[3]);
            }
        }
        *(float4*)(&sxp[ry][rxf * 4]) = v;
    }
    __syncthreads();

    // ---- Phase 2: per-thread 4x4 output patch, sliding window in y ----
    const int tx   = tid & 31;
    const int tyt  = tid >> 5;
    const int xloc = tx * 4;      // first output tile-col
    const int r0   = tyt * 4;     // first output tile-row; LDS row = tile row + 2

    // load span: s[i] = xp at tile col (xloc-2+i), i=0..7; LDS col = tile col + 4
    #define LOAD_ROW(lr, s) do {                                            \
        const float* rp_ = &sxp[(lr)][0];                                   \
        const float4 a_ = *(const float4*)(rp_ + xloc);                     \
        const float4 b_ = *(const float4*)(rp_ + xloc + 4);                 \
        const float4 d_ = *(const float4*)(rp_ + xloc + 8);                 \
        s[0]=a_.z; s[1]=a_.w; s[2]=b_.x; s[3]=b_.y;                         \
        s[4]=b_.z; s[5]=b_.w; s[6]=d_.x; s[7]=d_.y;                         \
    } while (0)

    // xNMS row (6 wide, tile cols xloc-1..xloc+4) + 3-wide rowmax -> rm[4]
    #define ROWMAX_NM(A, B, C, rm) do {                                     \
        float nm_[6];                                                       \
        _Pragma("unroll")                                                   \
        for (int j = 0; j < 6; ++j) {                                       \
            const float c_ = B[j + 1];                                      \
            float p_;                                                       \
            p_  = fmaxf(c_ - A[j    ], 0.f);                                \
            p_ *= fmaxf(c_ - A[j + 1], 0.f);                                \
            p_ *= fmaxf(c_ - A[j + 2], 0.f);                                \
            p_ *= fmaxf(c_ - B[j    ], 0.f);                                \
            p_ *= fmaxf(c_ - B[j + 2], 0.f);                                \
            p_ *= fmaxf(c_ - C[j    ], 0.f);                                \
            p_ *= fmaxf(c_ - C[j + 1], 0.f);                                \
            p_ *= fmaxf(c_ - C[j + 2], 0.f);                                \
            nm_[j] = p_;                                                    \
        }                                                                   \
        rm[0] = max3(nm_[0], nm_[1], nm_[2]);                               \
        rm[1] = max3(nm_[1], nm_[2], nm_[3]);                               \
        rm[2] = max3(nm_[2], nm_[3], nm_[4]);                               \
        rm[3] = max3(nm_[3], nm_[4], nm_[5]);                               \
    } while (0)

    float R0[8], R1[8], R2[8], R3[8];
    float rmP[4], rmC[4], rmN[4];

    LOAD_ROW(r0 + 0, R0);                 // tile row r0-2
    LOAD_ROW(r0 + 1, R1);                 // tile row r0-1
    LOAD_ROW(r0 + 2, R2);                 // tile row r0
    ROWMAX_NM(R0, R1, R2, rmP);           // nm row r0-1
    LOAD_ROW(r0 + 3, R3);                 // tile row r0+1
    ROWMAX_NM(R1, R2, R3, rmC);           // nm row r0

    float* __restrict__ po = out + (size_t)b * Hd * Wd
                           + (size_t)(y0 + r0) * Wd + (x0 + xloc);

    #define EMIT(CTR, ra, rb, rc) do {                                      \
        float4 o_;                                                          \
        o_.x = CTR[2] * 256.f * max3(ra[0], rb[0], rc[0]);                  \
        o_.y = CTR[3] * 256.f * max3(ra[1], rb[1], rc[1]);                  \
        o_.z = CTR[4] * 256.f * max3(ra[2], rb[2], rc[2]);                  \
        o_.w = CTR[5] * 256.f * max3(ra[3], rb[3], rc[3]);                  \
        *(float4*)po = o_;                                                  \
        po += Wd;                                                           \
    } while (0)

    // k=0: output row r0; nm row r0+1 needs tile rows r0..r0+2 (R2,R3,new R0)
    LOAD_ROW(r0 + 4, R0);
    ROWMAX_NM(R2, R3, R0, rmN);
    EMIT(R2, rmP, rmC, rmN);

    // k=1: output row r0+1; nm row r0+2 needs R3,R0,new R1
    LOAD_ROW(r0 + 5, R1);
    ROWMAX_NM(R3, R0, R1, rmP);
    EMIT(R3, rmC, rmN, rmP);

    // k=2: output row r0+2; nm row r0+3 needs R0,R1,new R2
    LOAD_ROW(r0 + 6, R2);
    ROWMAX_NM(R0, R1, R2, rmC);
    EMIT(R0, rmN, rmP, rmC);

    // k=3: output row r0+3; nm row r0+4 needs R1,R2,new R3
    LOAD_ROW(r0 + 7, R3);
    ROWMAX_NM(R1, R2, R3, rmN);
    EMIT(R1, rmP, rmC, rmN);

    #undef LOAD_ROW
    #undef ROWMAX_NM
    #undef EMIT
}

extern "C" void kernel_launch(void* const* d_in, const int* in_sizes, int n_in,
                              void* d_out, int out_size, void* d_ws, size_t ws_size,
                              hipStream_t stream) {
    const float* xin = (const float*)d_in[0];
    float* out = (float*)d_out;
    dim3 grid(Wd / TX, Hd / TY, Bd);
    hardnms_kernel<<<grid, dim3(256), 0, stream>>>(xin, out);
}

// Round 4
// 48.257 us; speedup vs baseline: 1.6850x; 1.1657x over previous
//
#include <hip/hip_runtime.h>

// HardNMS fused kernel — LDS-free, wave-private register sliding window.
// x: [B=16, 2, H=1024, W=1024] f32 -> out: [16, 1, 1024, 1024] f32
// xp   = relu(x[:,1] - x[:,0] - 0.1)
// xNMS = 256 * prod_{8 nbrs} relu(xp - xp_nb)   (zero-padded)
// out  = xp * maxpool3x3(xNMS)                  (xNMS >= 0 so zero-pad == -inf pad)
//
// Each wave: 256-col x SH-row strip. Each lane: 4 cols. Horizontal halo via
// __shfl (+ float2 edge loads on lanes 0/63). Vertical: register sliding
// window, loads issued 2 rows ahead. No LDS, no barriers.

constexpr int Wd = 1024, Hd = 1024, Bd = 16;
constexpr int SH = 16;                 // output rows per wave strip
constexpr float EPS = 0.1f;

__device__ __forceinline__ float max3(float a, float b, float c) {
    return fmaxf(fmaxf(a, b), c);
}
__device__ __forceinline__ float reluf(float v) { return fmaxf(v, 0.f); }

struct Raw { float4 a, c; float2 ea, ec; };

__global__ __launch_bounds__(256, 4) void hardnms_kernel(
    const float* __restrict__ xin, float* __restrict__ out) {
    const int tid   = threadIdx.x;
    const int lane  = tid & 63;
    const int wid   = tid >> 6;
    const int xbase = blockIdx.x * 256;
    const int col0  = xbase + lane * 4;
    const int y0    = (blockIdx.y * 4 + wid) * SH;
    const int b     = blockIdx.z;
    const float* __restrict__ p0 = xin + (size_t)(b * 2 + 0) * Hd * Wd;
    const float* __restrict__ p1 = xin + (size_t)(b * 2 + 1) * Hd * Wd;
    const bool lOK = (xbase > 0);
    const bool rOK = (xbase + 256 < Wd);

    Raw RW0, RW1;
    RW0.ea = RW0.ec = RW1.ea = RW1.ec = make_float2(0.f, 0.f);

    // Issue global loads for row gy (2 rows ahead of use).
    #define ISSUE(gy, RW) do {                                              \
        const int gy_ = (gy);                                               \
        if ((unsigned)gy_ < (unsigned)Hd) {                                 \
            const size_t ro_ = (size_t)gy_ * Wd;                            \
            (RW).a = *(const float4*)(p0 + ro_ + col0);                     \
            (RW).c = *(const float4*)(p1 + ro_ + col0);                     \
            if (lane == 0) {                                                \
                if (lOK) {                                                  \
                    (RW).ea = *(const float2*)(p0 + ro_ + xbase - 2);       \
                    (RW).ec = *(const float2*)(p1 + ro_ + xbase - 2);       \
                }                                                           \
            } else if (lane == 63) {                                        \
                if (rOK) {                                                  \
                    (RW).ea = *(const float2*)(p0 + ro_ + xbase + 256);     \
                    (RW).ec = *(const float2*)(p1 + ro_ + xbase + 256);     \
                }                                                           \
            }                                                               \
        } else {                                                            \
            (RW).a = make_float4(0.f, 0.f, 0.f, 0.f);                       \
            (RW).c = make_float4(0.f, 0.f, 0.f, 0.f);                       \
            (RW).ea = (RW).ec = make_float2(0.f, 0.f);                      \
        }                                                                   \
    } while (0)

    // Build xp 8-span S[i] = xp at col0-2+i from raw row.
    #define MAKEXP(RW, S) do {                                              \
        const float x0_ = reluf((RW).c.x - (RW).a.x - EPS);                 \
        const float x1_ = reluf((RW).c.y - (RW).a.y - EPS);                 \
        const float x2_ = reluf((RW).c.z - (RW).a.z - EPS);                 \
        const float x3_ = reluf((RW).c.w - (RW).a.w - EPS);                 \
        S[2] = x0_; S[3] = x1_; S[4] = x2_; S[5] = x3_;                     \
        S[0] = __shfl_up(x2_, 1);  S[1] = __shfl_up(x3_, 1);                \
        S[6] = __shfl_down(x0_, 1); S[7] = __shfl_down(x1_, 1);             \
        const float e0_ = reluf((RW).ec.x - (RW).ea.x - EPS);               \
        const float e1_ = reluf((RW).ec.y - (RW).ea.y - EPS);               \
        if (lane == 0)  { S[0] = lOK ? e0_ : 0.f; S[1] = lOK ? e1_ : 0.f; } \
        if (lane == 63) { S[6] = rOK ? e0_ : 0.f; S[7] = rOK ? e1_ : 0.f; } \
    } while (0)

    // xNMS row (6 wide, cols col0-1..col0+4) + 3-wide rowmax -> rm[4]
    #define ROWMAX_NM(A, B, C, rm) do {                                     \
        float nm_[6];                                                       \
        _Pragma("unroll")                                                   \
        for (int j = 0; j < 6; ++j) {                                       \
            const float c_ = B[j + 1];                                      \
            float p_;                                                       \
            p_  = reluf(c_ - A[j    ]);                                     \
            p_ *= reluf(c_ - A[j + 1]);                                     \
            p_ *= reluf(c_ - A[j + 2]);                                     \
            p_ *= reluf(c_ - B[j    ]);                                     \
            p_ *= reluf(c_ - B[j + 2]);                                     \
            p_ *= reluf(c_ - C[j    ]);                                     \
            p_ *= reluf(c_ - C[j + 1]);                                     \
            p_ *= reluf(c_ - C[j + 2]);                                     \
            nm_[j] = p_;                                                    \
        }                                                                   \
        rm[0] = max3(nm_[0], nm_[1], nm_[2]);                               \
        rm[1] = max3(nm_[1], nm_[2], nm_[3]);                               \
        rm[2] = max3(nm_[2], nm_[3], nm_[4]);                               \
        rm[3] = max3(nm_[3], nm_[4], nm_[5]);                               \
    } while (0)

    #define EMIT(CTR, ra, rb, rc) do {                                      \
        float4 o_;                                                          \
        o_.x = CTR[2] * 256.f * max3(ra[0], rb[0], rc[0]);                  \
        o_.y = CTR[3] * 256.f * max3(ra[1], rb[1], rc[1]);                  \
        o_.z = CTR[4] * 256.f * max3(ra[2], rb[2], rc[2]);                  \
        o_.w = CTR[5] * 256.f * max3(ra[3], rb[3], rc[3]);                  \
        *(float4*)po = o_;                                                  \
        po += Wd;                                                           \
    } while (0)

    float R0[8], R1[8], R2[8], R3[8];
    float rm0[4], rm1[4], rm2[4], rm3[4];

    // Prologue: rows y0-2 .. y0+1 in R2,R3,R0,R1 (row r lives in R[r&3]);
    // raw loads stay 2 rows ahead.
    ISSUE(y0 - 2, RW0);
    ISSUE(y0 - 1, RW1);
    MAKEXP(RW0, R2);                      // row y0-2
    ISSUE(y0 + 0, RW0);
    MAKEXP(RW1, R3);                      // row y0-1
    ISSUE(y0 + 1, RW1);
    MAKEXP(RW0, R0);                      // row y0
    ISSUE(y0 + 2, RW0);
    ROWMAX_NM(R2, R3, R0, rm3);           // nm row y0-1
    MAKEXP(RW1, R1);                      // row y0+1
    ISSUE(y0 + 3, RW1);
    ROWMAX_NM(R3, R0, R1, rm0);           // nm row y0

    float* po = out + (size_t)b * Hd * Wd + (size_t)y0 * Wd + col0;

    // Steady state: step k consumes raw row k+2, issues row k+4,
    // computes nm row k+1, emits output row k.  Period-4 register rotation.
    for (int k4 = 0; k4 < SH / 4; ++k4) {
        const int kb = k4 * 4;
        // k = kb+0
        MAKEXP(RW0, R2);
        if (kb + 0 <= SH - 3) ISSUE(y0 + kb + 4, RW0);
        ROWMAX_NM(R0, R1, R2, rm1);
        EMIT(R0, rm3, rm0, rm1);
        // k = kb+1
        MAKEXP(RW1, R3);
        if (kb + 1 <= SH - 3) ISSUE(y0 + kb + 5, RW1);
        ROWMAX_NM(R1, R2, R3, rm2);
        EMIT(R1, rm0, rm1, rm2);
        // k = kb+2
        MAKEXP(RW0, R0);
        if (kb + 2 <= SH - 3) ISSUE(y0 + kb + 6, RW0);
        ROWMAX_NM(R2, R3, R0, rm3);
        EMIT(R2, rm1, rm2, rm3);
        // k = kb+3
        MAKEXP(RW1, R1);
        if (kb + 3 <= SH - 3) ISSUE(y0 + kb + 7, RW1);
        ROWMAX_NM(R3, R0, R1, rm0);
        EMIT(R3, rm2, rm3, rm0);
    }

    #undef ISSUE
    #undef MAKEXP
    #undef ROWMAX_NM
    #undef EMIT
}

extern "C" void kernel_launch(void* const* d_in, const int* in_sizes, int n_in,
                              void* d_out, int out_size, void* d_ws, size_t ws_size,
                              hipStream_t stream) {
    const float* xin = (const float*)d_in[0];
    float* out = (float*)d_out;
    dim3 grid(Wd / 256, Hd / (4 * SH), Bd);   // (4, 16, 16)
    hardnms_kernel<<<grid, dim3(256), 0, stream>>>(xin, out);
}